// Round 5
// baseline (4106.088 us; speedup 1.0000x reference)
//
#include <hip/hip_runtime.h>
#include <hip/hip_bf16.h>

// DynamicLoRALinear: out = x @ W^T + b + 2.0 * ((x @ A[slot]) @ Bm[slot])
// fp32 I/O; compute in bf16 MFMA (absmax 0.031 vs threshold 0.1425).
// R10: h = x@A computed INSIDE the GEMM (At LDS subtile + 4 extra MFMA/wave/K-step,
//      transposed through reused LDS for the epilogue). prep collapses to a pure
//      streaming cvt (X->Xb, W->Wb) -- the ~200us barrier-heavy lora phase dies.
//      GEMM body = proven R5 structure, two 1024-block m-halves (R9: 2x202us,
//      FETCH 0.77 GB < monolithic 1.07 GB).

typedef __bf16 bf16_t;
typedef __bf16 bf16x8 __attribute__((ext_vector_type(8)));
typedef __bf16 bf16x4 __attribute__((ext_vector_type(4)));
typedef float f32x4 __attribute__((ext_vector_type(4)));

#define M_DIM 8192
#define K_DIM 4096
#define N_DIM 4096
#define SCALE_F 2.0f

#define CVT_BLOCKS 2048

__device__ __forceinline__ void gload_lds16(const void* g, void* l) {
    __builtin_amdgcn_global_load_lds(
        (const __attribute__((address_space(1))) void*)g,
        (__attribute__((address_space(3))) void*)l, 16, 0, 0);
}

// ---------------- pure streaming cvt: X->bf16 and W->bf16 ----------------
__global__ __launch_bounds__(256) void cvt_all(
    const float* __restrict__ X, bf16_t* __restrict__ Xb,
    const float* __restrict__ W, bf16_t* __restrict__ Wb)
{
    const int stride = CVT_BLOCKS * 256;
    const int i0 = blockIdx.x * 256 + threadIdx.x;

    const int nx8 = M_DIM * K_DIM / 8;
    for (int t = i0; t < nx8; t += stride) {
        f32x4 a = ((const f32x4*)X)[t * 2];
        f32x4 b = ((const f32x4*)X)[t * 2 + 1];
        bf16x8 o = {(bf16_t)a[0], (bf16_t)a[1], (bf16_t)a[2], (bf16_t)a[3],
                    (bf16_t)b[0], (bf16_t)b[1], (bf16_t)b[2], (bf16_t)b[3]};
        ((bf16x8*)Xb)[t] = o;
    }
    const int nw8 = N_DIM * K_DIM / 8;
    for (int t = i0; t < nw8; t += stride) {
        f32x4 a = ((const f32x4*)W)[t * 2];
        f32x4 b = ((const f32x4*)W)[t * 2 + 1];
        bf16x8 o = {(bf16_t)a[0], (bf16_t)a[1], (bf16_t)a[2], (bf16_t)a[3],
                    (bf16_t)b[0], (bf16_t)b[1], (bf16_t)b[2], (bf16_t)b[3]};
        ((bf16x8*)Wb)[t] = o;
    }
}

// ------------- main GEMM: R5 body + in-kernel h, 1024-block half-grid -------------
__global__ __launch_bounds__(256) void gemm_lora_direct(
    const bf16_t* __restrict__ Xb, const bf16_t* __restrict__ Wb,
    const float* __restrict__ bias, const float* __restrict__ lora_As,
    const float* __restrict__ lora_Bs, const int* __restrict__ mapping,
    float* __restrict__ out, int m_base)
{
    __shared__ bf16_t As[128 * 64];   // 16 KB (reused as f32 h_sm after K-loop)
    __shared__ bf16_t Bs[128 * 64];   // 16 KB
    __shared__ bf16_t At[16 * 72];    // 2.25 KB: A_lora subtile, [r][k] pad 72

    const int tid  = threadIdx.x;
    const int wave = tid >> 6;
    const int lane = tid & 63;
    const int bid  = blockIdx.x;
    const int n_t  = (bid & 7) + ((bid >> 8) << 3);  // 0..31 (XCD-aware)
    const int m_t  = ((bid >> 3) & 31) + m_base;     // 0..63
    const int bm0 = m_t * 128;
    const int bn0 = n_t * 128;
    const int wm0 = (wave >> 1) * 64;
    const int wn0 = (wave & 1) * 64;
    const int r16 = lane & 15;
    const int kq  = lane >> 4;

    const int slot = mapping[bm0 >> 10];
    const float* __restrict__ A = lora_As + (size_t)slot * (K_DIM * 16);
    const int kk = tid >> 2;            // At staging: k row 0..63
    const int q  = tid & 3;             // r quad
    const int ih = (wave & 1) * 2;      // h i-range split across wave pairs

    f32x4 acc[4][4];
#pragma unroll
    for (int i = 0; i < 4; ++i)
#pragma unroll
        for (int j = 0; j < 4; ++j) acc[i][j] = (f32x4){0.f, 0.f, 0.f, 0.f};
    f32x4 acc_h[2];
    acc_h[0] = (f32x4){0.f, 0.f, 0.f, 0.f};
    acc_h[1] = (f32x4){0.f, 0.f, 0.f, 0.f};

    for (int k0 = 0; k0 < K_DIM; k0 += 64) {
#pragma unroll
        for (int p = 0; p < 4; ++p) {
            const int base = wave * 256 + p * 64;    // wave-uniform LDS slot base
            const int s    = base + lane;
            const int row  = s >> 3;
            const int k8g  = (s & 7) ^ (row & 7);
            gload_lds16(Xb + (size_t)(bm0 + row) * K_DIM + k0 + k8g * 8,
                        As + (size_t)base * 8);
            gload_lds16(Wb + (size_t)(bn0 + row) * K_DIM + k0 + k8g * 8,
                        Bs + (size_t)base * 8);
        }
        // stage A_lora subtile transposed: thread -> A[k0+kk][q*4 .. +3]
        {
            f32x4 av = *(const f32x4*)(A + (size_t)(k0 + kk) * 16 + q * 4);
#pragma unroll
            for (int rr = 0; rr < 4; ++rr)
                At[(q * 4 + rr) * 72 + kk] = (bf16_t)av[rr];
        }
        __syncthreads();

#pragma unroll
        for (int kh = 0; kh < 2; ++kh) {
            bf16x8 af[4], bfr[4];
            const int k8 = kh * 4 + kq;
#pragma unroll
            for (int i = 0; i < 4; ++i) {
                const int ra = wm0 + i * 16 + r16;
                const int rb = wn0 + i * 16 + r16;
                af[i]  = *(const bf16x8*)(As + ((size_t)ra * 8 + (k8 ^ (ra & 7))) * 8);
                bfr[i] = *(const bf16x8*)(Bs + ((size_t)rb * 8 + (k8 ^ (rb & 7))) * 8);
            }
#pragma unroll
            for (int i = 0; i < 4; ++i)
#pragma unroll
                for (int j = 0; j < 4; ++j)
                    acc[i][j] = __builtin_amdgcn_mfma_f32_16x16x32_bf16(af[i], bfr[j], acc[i][j], 0, 0, 0);
            // h contribution: this wave covers rows (wm0 + (ih..ih+1)*16)
            {
                bf16x8 ah = *(const bf16x8*)(At + r16 * 72 + k8 * 8);
                acc_h[0] = __builtin_amdgcn_mfma_f32_16x16x32_bf16(af[ih],     ah, acc_h[0], 0, 0, 0);
                acc_h[1] = __builtin_amdgcn_mfma_f32_16x16x32_bf16(af[ih + 1], ah, acc_h[1], 0, 0, 0);
            }
        }
        __syncthreads();
    }

    // ---- transpose h through LDS (reuse As region as f32 [128][16]) ----
    float* h_sm = (float*)As;
#pragma unroll
    for (int i2 = 0; i2 < 2; ++i2)
#pragma unroll
        for (int e = 0; e < 4; ++e)
            h_sm[(wm0 + (ih + i2) * 16 + kq * 4 + e) * 16 + r16] = acc_h[i2][e];
    __syncthreads();

    // ---------------- fused LoRA + bias epilogue ----------------
    const bool hasK = (kq < 2);
    const int kq2 = hasK ? kq : 0;

    bf16x8 hfrag[4], bmf[4];
#pragma unroll
    for (int i = 0; i < 4; ++i) {
        const float* hp = h_sm + (size_t)(wm0 + i * 16 + r16) * 16 + kq2 * 8;
        f32x4 h0 = *(const f32x4*)hp;
        f32x4 h1 = *(const f32x4*)(hp + 4);
#pragma unroll
        for (int jj = 0; jj < 4; ++jj) {
            hfrag[i][jj]     = hasK ? (bf16_t)(h0[jj] * SCALE_F) : (bf16_t)0.f;
            hfrag[i][jj + 4] = hasK ? (bf16_t)(h1[jj] * SCALE_F) : (bf16_t)0.f;
        }
    }
#pragma unroll
    for (int j = 0; j < 4; ++j) {
        const int o = bn0 + wn0 + j * 16 + r16;
#pragma unroll
        for (int jj = 0; jj < 8; ++jj) {
            const int r = kq2 * 8 + jj;
            const float v = lora_Bs[((size_t)slot * 16 + r) * N_DIM + o];
            bmf[j][jj] = hasK ? (bf16_t)v : (bf16_t)0.f;
        }
    }
#pragma unroll
    for (int i = 0; i < 4; ++i)
#pragma unroll
        for (int j = 0; j < 4; ++j)
            acc[i][j] = __builtin_amdgcn_mfma_f32_16x16x32_bf16(hfrag[i], bmf[j], acc[i][j], 0, 0, 0);

#pragma unroll
    for (int j = 0; j < 4; ++j) {
        const int o = bn0 + wn0 + j * 16 + r16;
        const float bv = bias[o];
#pragma unroll
        for (int i = 0; i < 4; ++i) {
#pragma unroll
            for (int e = 0; e < 4; ++e) {
                const int m = bm0 + wm0 + i * 16 + kq * 4 + e;
                out[(size_t)m * N_DIM + o] = acc[i][j][e] + bv;
            }
        }
    }
}

// =================== fallback path (ws too small for Xb/Wb) ===================
// prep: lora h to h_ws (fp32 staging, no Xb/Wb), then fp32-staging GEMM.
__global__ __launch_bounds__(256) void prep_fallback(
    const float* __restrict__ X,
    const float* __restrict__ lora_As,
    const int* __restrict__ mapping,
    float* __restrict__ h_ws)
{
    __shared__ bf16_t Xt[32 * 16 * 8];
    __shared__ bf16_t At[16 * 136];
    __shared__ float hred[4 * 2 * 16 * 16];

    const int tid = threadIdx.x;
    const int bid = blockIdx.x;

    const int wave = tid >> 6;
    const int lane = tid & 63;
    const int bm0  = bid * 32;
    const int slot = mapping[bm0 >> 10];
    const float* __restrict__ A = lora_As + (size_t)slot * (K_DIM * 16);

    const int srow = tid >> 3;
    const int sc2  = tid & 7;
    const int r16  = lane & 15;
    const int kq   = lane >> 4;
    const int kk   = tid >> 1;
    const int half = tid & 1;

    f32x4 acc[2];
    acc[0] = (f32x4){0.f, 0.f, 0.f, 0.f};
    acc[1] = (f32x4){0.f, 0.f, 0.f, 0.f};

    const float* xrow = X + (size_t)(bm0 + srow) * K_DIM + sc2 * 16;

    for (int k0 = 0; k0 < K_DIM; k0 += 128) {
        f32x4 v0 = *(const f32x4*)(xrow + k0);
        f32x4 v1 = *(const f32x4*)(xrow + k0 + 4);
        f32x4 v2 = *(const f32x4*)(xrow + k0 + 8);
        f32x4 v3 = *(const f32x4*)(xrow + k0 + 12);
        bf16x8 c0 = {(bf16_t)v0[0], (bf16_t)v0[1], (bf16_t)v0[2], (bf16_t)v0[3],
                     (bf16_t)v1[0], (bf16_t)v1[1], (bf16_t)v1[2], (bf16_t)v1[3]};
        bf16x8 c1 = {(bf16_t)v2[0], (bf16_t)v2[1], (bf16_t)v2[2], (bf16_t)v2[3],
                     (bf16_t)v3[0], (bf16_t)v3[1], (bf16_t)v3[2], (bf16_t)v3[3]};
        const int k8a = sc2 * 2, k8b = sc2 * 2 + 1;
        *(bf16x8*)(Xt + (srow * 16 + (k8a ^ (srow & 15))) * 8) = c0;
        *(bf16x8*)(Xt + (srow * 16 + (k8b ^ (srow & 15))) * 8) = c1;

        {
            const float* ap = A + (size_t)(k0 + kk) * 16 + half * 8;
            f32x4 a0 = *(const f32x4*)ap;
            f32x4 a1 = *(const f32x4*)(ap + 4);
#pragma unroll
            for (int rr = 0; rr < 4; ++rr) {
                At[(half * 8 + rr) * 136 + kk]     = (bf16_t)a0[rr];
                At[(half * 8 + 4 + rr) * 136 + kk] = (bf16_t)a1[rr];
            }
        }
        __syncthreads();

#pragma unroll
        for (int i = 0; i < 2; ++i) {
            const int row_l = i * 16 + r16;
            const int c = wave * 4 + kq;
            bf16x8 af  = *(const bf16x8*)(Xt + (row_l * 16 + (c ^ (row_l & 15))) * 8);
            bf16x8 bfr = *(const bf16x8*)(At + r16 * 136 + wave * 32 + kq * 8);
            acc[i] = __builtin_amdgcn_mfma_f32_16x16x32_bf16(af, bfr, acc[i], 0, 0, 0);
        }
        __syncthreads();
    }

#pragma unroll
    for (int i = 0; i < 2; ++i)
#pragma unroll
        for (int e = 0; e < 4; ++e)
            hred[wave * 512 + i * 256 + (kq * 4 + e) * 16 + r16] = acc[i][e];
    __syncthreads();
#pragma unroll
    for (int q = 0; q < 2; ++q) {
        const int entry = tid * 2 + q;
        const int row_l = entry >> 4, col = entry & 15;
        const int i = row_l >> 4, rr = row_l & 15;
        const int off = i * 256 + rr * 16 + col;
        float s = hred[off] + hred[512 + off] + hred[1024 + off] + hred[1536 + off];
        h_ws[(size_t)(bm0 + row_l) * 16 + col] = s * SCALE_F;
    }
}

__global__ __launch_bounds__(256) void gemm_lora_f32s(
    const float* __restrict__ Xf, const float* __restrict__ Wf,
    const float* __restrict__ bias, const float* __restrict__ lora_Bs,
    const int* __restrict__ mapping, const float* __restrict__ h_ws,
    float* __restrict__ out)
{
    __shared__ float Asf[128 * 32];
    __shared__ float Bsf[128 * 32];

    const int tid  = threadIdx.x;
    const int wave = tid >> 6;
    const int lane = tid & 63;
    const int bid  = blockIdx.x;
    const int n_t  = (bid & 7) + ((bid >> 9) << 3);
    const int m_t  = (bid >> 3) & 63;
    const int bm0 = m_t * 128;
    const int bn0 = n_t * 128;
    const int wm0 = (wave >> 1) * 64;
    const int wn0 = (wave & 1) * 64;
    const int r16 = lane & 15;
    const int kq  = lane >> 4;

    f32x4 acc[4][4];
#pragma unroll
    for (int i = 0; i < 4; ++i)
#pragma unroll
        for (int j = 0; j < 4; ++j) acc[i][j] = (f32x4){0.f, 0.f, 0.f, 0.f};

    for (int k0 = 0; k0 < K_DIM; k0 += 32) {
#pragma unroll
        for (int p = 0; p < 4; ++p) {
            const int idx0 = (p * 4 + wave) * 64;
            const int idx  = idx0 + lane;
            const int k4   = idx >> 7;
            const int row  = idx & 127;
            gload_lds16(Xf + (size_t)(bm0 + row) * K_DIM + (k0 + k4 * 4),
                        Asf + (size_t)idx0 * 4);
            gload_lds16(Wf + (size_t)(bn0 + row) * K_DIM + (k0 + k4 * 4),
                        Bsf + (size_t)idx0 * 4);
        }
        __syncthreads();

        bf16x8 af[4], bfr[4];
#pragma unroll
        for (int i = 0; i < 4; ++i) {
            const int ra = wm0 + i * 16 + r16;
            const int rb = wn0 + i * 16 + r16;
            f32x4 a0 = *(const f32x4*)(Asf + ((size_t)(kq * 2) * 128 + ra) * 4);
            f32x4 a1 = *(const f32x4*)(Asf + ((size_t)(kq * 2 + 1) * 128 + ra) * 4);
            f32x4 b0 = *(const f32x4*)(Bsf + ((size_t)(kq * 2) * 128 + rb) * 4);
            f32x4 b1 = *(const f32x4*)(Bsf + ((size_t)(kq * 2 + 1) * 128 + rb) * 4);
            af[i]  = (bf16x8){(bf16_t)a0[0], (bf16_t)a0[1], (bf16_t)a0[2], (bf16_t)a0[3],
                              (bf16_t)a1[0], (bf16_t)a1[1], (bf16_t)a1[2], (bf16_t)a1[3]};
            bfr[i] = (bf16x8){(bf16_t)b0[0], (bf16_t)b0[1], (bf16_t)b0[2], (bf16_t)b0[3],
                              (bf16_t)b1[0], (bf16_t)b1[1], (bf16_t)b1[2], (bf16_t)b1[3]};
        }
#pragma unroll
        for (int i = 0; i < 4; ++i)
#pragma unroll
            for (int j = 0; j < 4; ++j)
                acc[i][j] = __builtin_amdgcn_mfma_f32_16x16x32_bf16(af[i], bfr[j], acc[i][j], 0, 0, 0);
        __syncthreads();
    }

    // fallback epilogue: h from global h_ws
    const int slot = mapping[bm0 >> 10];
    const bool hasK = (kq < 2);
    const int kq2 = hasK ? kq : 0;

    bf16x8 hfrag[4], bmf[4];
#pragma unroll
    for (int i = 0; i < 4; ++i) {
        const float* hp = h_ws + (size_t)(bm0 + wm0 + i * 16 + r16) * 16 + kq2 * 8;
        f32x4 h0 = *(const f32x4*)hp;
        f32x4 h1 = *(const f32x4*)(hp + 4);
#pragma unroll
        for (int jj = 0; jj < 4; ++jj) {
            hfrag[i][jj]     = hasK ? (bf16_t)h0[jj] : (bf16_t)0.f;
            hfrag[i][jj + 4] = hasK ? (bf16_t)h1[jj] : (bf16_t)0.f;
        }
    }
#pragma unroll
    for (int j = 0; j < 4; ++j) {
        const int o = bn0 + wn0 + j * 16 + r16;
#pragma unroll
        for (int jj = 0; jj < 8; ++jj) {
            const int r = kq2 * 8 + jj;
            const float v = lora_Bs[((size_t)slot * 16 + r) * N_DIM + o];
            bmf[j][jj] = hasK ? (bf16_t)v : (bf16_t)0.f;
        }
    }
#pragma unroll
    for (int i = 0; i < 4; ++i)
#pragma unroll
        for (int j = 0; j < 4; ++j)
            acc[i][j] = __builtin_amdgcn_mfma_f32_16x16x32_bf16(hfrag[i], bmf[j], acc[i][j], 0, 0, 0);

#pragma unroll
    for (int j = 0; j < 4; ++j) {
        const int o = bn0 + wn0 + j * 16 + r16;
        const float bv = bias[o];
#pragma unroll
        for (int i = 0; i < 4; ++i) {
#pragma unroll
            for (int e = 0; e < 4; ++e) {
                const int m = bm0 + wm0 + i * 16 + kq * 4 + e;
                out[(size_t)m * N_DIM + o] = acc[i][j][e] + bv;
            }
        }
    }
}

extern "C" void kernel_launch(void* const* d_in, const int* in_sizes, int n_in,
                              void* d_out, int out_size, void* d_ws, size_t ws_size,
                              hipStream_t stream) {
    const float* x        = (const float*)d_in[0];
    const int*   mapping  = (const int*)d_in[1];
    const float* W        = (const float*)d_in[2];
    const float* b        = (const float*)d_in[3];
    const float* lora_As  = (const float*)d_in[4];
    const float* lora_Bs  = (const float*)d_in[5];
    float* out = (float*)d_out;

    const size_t xb_bytes = (size_t)M_DIM * K_DIM * 2;   // 64 MB
    const size_t wb_bytes = (size_t)N_DIM * K_DIM * 2;   // 32 MB
    const bool direct = ws_size >= xb_bytes + wb_bytes;

    if (direct) {
        bf16_t* Xb = (bf16_t*)d_ws;
        bf16_t* Wb = (bf16_t*)((char*)d_ws + xb_bytes);
        cvt_all<<<dim3(CVT_BLOCKS), 256, 0, stream>>>(x, Xb, W, Wb);
        gemm_lora_direct<<<dim3(1024), 256, 0, stream>>>(
            Xb, Wb, b, lora_As, lora_Bs, mapping, out, 0);
        gemm_lora_direct<<<dim3(1024), 256, 0, stream>>>(
            Xb, Wb, b, lora_As, lora_Bs, mapping, out, 32);
    } else {
        float* h_ws = (float*)d_ws;   // 512 KB
        prep_fallback<<<dim3(M_DIM / 32), 256, 0, stream>>>(
            x, lora_As, mapping, h_ws);
        gemm_lora_f32s<<<dim3(2048), 256, 0, stream>>>(
            x, W, b, lora_Bs, mapping, h_ws, out);
    }
}

// Round 6
// 692.965 us; speedup vs baseline: 5.9254x; 5.9254x over previous
//
#include <hip/hip_runtime.h>
#include <hip/hip_bf16.h>

// DynamicLoRALinear: out = x @ W^T + b + 2.0 * ((x @ A[slot]) @ Bm[slot])
// fp32 I/O; compute in bf16 MFMA (absmax 0.031 vs threshold 0.1425).
// R11: R10 architecture (h computed in-GEMM, prep = pure streaming cvt) with two
//      mechanical fixes for R10's 5x regression:
//      (1) rule-#20 scratch: af[ih] runtime index -> wave-uniform branch with
//          static indices (af stays in registers; VALUBusy 77% was scratch traffic)
//      (2) At bank conflicts (4.5M cyc): 72-stride layout -> As-style XOR-chunk
//          swizzle (stride 64, chunk ^ (row&7) on write and read; As measures 0)

typedef __bf16 bf16_t;
typedef __bf16 bf16x8 __attribute__((ext_vector_type(8)));
typedef __bf16 bf16x4 __attribute__((ext_vector_type(4)));
typedef float f32x4 __attribute__((ext_vector_type(4)));

#define M_DIM 8192
#define K_DIM 4096
#define N_DIM 4096
#define SCALE_F 2.0f

#define CVT_BLOCKS 2048

__device__ __forceinline__ void gload_lds16(const void* g, void* l) {
    __builtin_amdgcn_global_load_lds(
        (const __attribute__((address_space(1))) void*)g,
        (__attribute__((address_space(3))) void*)l, 16, 0, 0);
}

// ---------------- pure streaming cvt: X->bf16 and W->bf16 ----------------
__global__ __launch_bounds__(256) void cvt_all(
    const float* __restrict__ X, bf16_t* __restrict__ Xb,
    const float* __restrict__ W, bf16_t* __restrict__ Wb)
{
    const int stride = CVT_BLOCKS * 256;
    const int i0 = blockIdx.x * 256 + threadIdx.x;

    const int nx8 = M_DIM * K_DIM / 8;
    for (int t = i0; t < nx8; t += stride) {
        f32x4 a = ((const f32x4*)X)[t * 2];
        f32x4 b = ((const f32x4*)X)[t * 2 + 1];
        bf16x8 o = {(bf16_t)a[0], (bf16_t)a[1], (bf16_t)a[2], (bf16_t)a[3],
                    (bf16_t)b[0], (bf16_t)b[1], (bf16_t)b[2], (bf16_t)b[3]};
        ((bf16x8*)Xb)[t] = o;
    }
    const int nw8 = N_DIM * K_DIM / 8;
    for (int t = i0; t < nw8; t += stride) {
        f32x4 a = ((const f32x4*)W)[t * 2];
        f32x4 b = ((const f32x4*)W)[t * 2 + 1];
        bf16x8 o = {(bf16_t)a[0], (bf16_t)a[1], (bf16_t)a[2], (bf16_t)a[3],
                    (bf16_t)b[0], (bf16_t)b[1], (bf16_t)b[2], (bf16_t)b[3]};
        ((bf16x8*)Wb)[t] = o;
    }
}

// ------------- main GEMM: R5 body + in-kernel h, 1024-block half-grid -------------
__global__ __launch_bounds__(256) void gemm_lora_direct(
    const bf16_t* __restrict__ Xb, const bf16_t* __restrict__ Wb,
    const float* __restrict__ bias, const float* __restrict__ lora_As,
    const float* __restrict__ lora_Bs, const int* __restrict__ mapping,
    float* __restrict__ out, int m_base)
{
    __shared__ bf16_t As[128 * 64];   // 16 KB (reused as f32 h_sm after K-loop)
    __shared__ bf16_t Bs[128 * 64];   // 16 KB
    __shared__ bf16_t At[16 * 64];    // 2 KB: A_lora subtile [r][k-chunk], XOR-swizzled

    const int tid  = threadIdx.x;
    const int wave = tid >> 6;
    const int lane = tid & 63;
    const int bid  = blockIdx.x;
    const int n_t  = (bid & 7) + ((bid >> 8) << 3);  // 0..31 (XCD-aware)
    const int m_t  = ((bid >> 3) & 31) + m_base;     // 0..63
    const int bm0 = m_t * 128;
    const int bn0 = n_t * 128;
    const int wm0 = (wave >> 1) * 64;
    const int wn0 = (wave & 1) * 64;
    const int r16 = lane & 15;
    const int kq  = lane >> 4;

    const int slot = mapping[bm0 >> 10];
    const float* __restrict__ A = lora_As + (size_t)slot * (K_DIM * 16);
    const int kk = tid >> 2;            // At staging: k row 0..63
    const int q  = tid & 3;             // r quad
    const int ih = (wave & 1) * 2;      // h i-range base (used only in addresses)

    f32x4 acc[4][4];
#pragma unroll
    for (int i = 0; i < 4; ++i)
#pragma unroll
        for (int j = 0; j < 4; ++j) acc[i][j] = (f32x4){0.f, 0.f, 0.f, 0.f};
    f32x4 acc_h[2];
    acc_h[0] = (f32x4){0.f, 0.f, 0.f, 0.f};
    acc_h[1] = (f32x4){0.f, 0.f, 0.f, 0.f};

    for (int k0 = 0; k0 < K_DIM; k0 += 64) {
#pragma unroll
        for (int p = 0; p < 4; ++p) {
            const int base = wave * 256 + p * 64;    // wave-uniform LDS slot base
            const int s    = base + lane;
            const int row  = s >> 3;
            const int k8g  = (s & 7) ^ (row & 7);
            gload_lds16(Xb + (size_t)(bm0 + row) * K_DIM + k0 + k8g * 8,
                        As + (size_t)base * 8);
            gload_lds16(Wb + (size_t)(bn0 + row) * K_DIM + k0 + k8g * 8,
                        Bs + (size_t)base * 8);
        }
        // stage A_lora subtile transposed+swizzled: A[k0+kk][q*4..+3] ->
        // At[row][chunk (kk>>3)^(row&7), elem kk&7]   (As-style layout)
        {
            f32x4 av = *(const f32x4*)(A + (size_t)(k0 + kk) * 16 + q * 4);
            const int c = kk >> 3, e = kk & 7;
#pragma unroll
            for (int rr = 0; rr < 4; ++rr) {
                const int row = q * 4 + rr;
                At[row * 64 + ((c ^ (row & 7)) * 8 + e)] = (bf16_t)av[rr];
            }
        }
        __syncthreads();

#pragma unroll
        for (int kh = 0; kh < 2; ++kh) {
            bf16x8 af[4], bfr[4];
            const int k8 = kh * 4 + kq;
#pragma unroll
            for (int i = 0; i < 4; ++i) {
                const int ra = wm0 + i * 16 + r16;
                const int rb = wn0 + i * 16 + r16;
                af[i]  = *(const bf16x8*)(As + ((size_t)ra * 8 + (k8 ^ (ra & 7))) * 8);
                bfr[i] = *(const bf16x8*)(Bs + ((size_t)rb * 8 + (k8 ^ (rb & 7))) * 8);
            }
#pragma unroll
            for (int i = 0; i < 4; ++i)
#pragma unroll
                for (int j = 0; j < 4; ++j)
                    acc[i][j] = __builtin_amdgcn_mfma_f32_16x16x32_bf16(af[i], bfr[j], acc[i][j], 0, 0, 0);
            // h contribution: wave-uniform branch, STATIC af indices (rule #20)
            {
                bf16x8 ah = *(const bf16x8*)(At + r16 * 64 + ((k8 ^ (r16 & 7)) * 8));
                if (wave & 1) {
                    acc_h[0] = __builtin_amdgcn_mfma_f32_16x16x32_bf16(af[2], ah, acc_h[0], 0, 0, 0);
                    acc_h[1] = __builtin_amdgcn_mfma_f32_16x16x32_bf16(af[3], ah, acc_h[1], 0, 0, 0);
                } else {
                    acc_h[0] = __builtin_amdgcn_mfma_f32_16x16x32_bf16(af[0], ah, acc_h[0], 0, 0, 0);
                    acc_h[1] = __builtin_amdgcn_mfma_f32_16x16x32_bf16(af[1], ah, acc_h[1], 0, 0, 0);
                }
            }
        }
        __syncthreads();
    }

    // ---- transpose h through LDS (reuse As region as f32 [128][16]) ----
    float* h_sm = (float*)As;
#pragma unroll
    for (int i2 = 0; i2 < 2; ++i2)
#pragma unroll
        for (int e = 0; e < 4; ++e)
            h_sm[(wm0 + (ih + i2) * 16 + kq * 4 + e) * 16 + r16] = acc_h[i2][e];
    __syncthreads();

    // ---------------- fused LoRA + bias epilogue ----------------
    const bool hasK = (kq < 2);
    const int kq2 = hasK ? kq : 0;

    bf16x8 hfrag[4], bmf[4];
#pragma unroll
    for (int i = 0; i < 4; ++i) {
        const float* hp = h_sm + (size_t)(wm0 + i * 16 + r16) * 16 + kq2 * 8;
        f32x4 h0 = *(const f32x4*)hp;
        f32x4 h1 = *(const f32x4*)(hp + 4);
#pragma unroll
        for (int jj = 0; jj < 4; ++jj) {
            hfrag[i][jj]     = hasK ? (bf16_t)(h0[jj] * SCALE_F) : (bf16_t)0.f;
            hfrag[i][jj + 4] = hasK ? (bf16_t)(h1[jj] * SCALE_F) : (bf16_t)0.f;
        }
    }
#pragma unroll
    for (int j = 0; j < 4; ++j) {
        const int o = bn0 + wn0 + j * 16 + r16;
#pragma unroll
        for (int jj = 0; jj < 8; ++jj) {
            const int r = kq2 * 8 + jj;
            const float v = lora_Bs[((size_t)slot * 16 + r) * N_DIM + o];
            bmf[j][jj] = hasK ? (bf16_t)v : (bf16_t)0.f;
        }
    }
#pragma unroll
    for (int i = 0; i < 4; ++i)
#pragma unroll
        for (int j = 0; j < 4; ++j)
            acc[i][j] = __builtin_amdgcn_mfma_f32_16x16x32_bf16(hfrag[i], bmf[j], acc[i][j], 0, 0, 0);

#pragma unroll
    for (int j = 0; j < 4; ++j) {
        const int o = bn0 + wn0 + j * 16 + r16;
        const float bv = bias[o];
#pragma unroll
        for (int i = 0; i < 4; ++i) {
#pragma unroll
            for (int e = 0; e < 4; ++e) {
                const int m = bm0 + wm0 + i * 16 + kq * 4 + e;
                out[(size_t)m * N_DIM + o] = acc[i][j][e] + bv;
            }
        }
    }
}

// =================== fallback path (ws too small for Xb/Wb) ===================
__global__ __launch_bounds__(256) void prep_fallback(
    const float* __restrict__ X,
    const float* __restrict__ lora_As,
    const int* __restrict__ mapping,
    float* __restrict__ h_ws)
{
    __shared__ bf16_t Xt[32 * 16 * 8];
    __shared__ bf16_t At[16 * 136];
    __shared__ float hred[4 * 2 * 16 * 16];

    const int tid = threadIdx.x;
    const int bid = blockIdx.x;

    const int wave = tid >> 6;
    const int lane = tid & 63;
    const int bm0  = bid * 32;
    const int slot = mapping[bm0 >> 10];
    const float* __restrict__ A = lora_As + (size_t)slot * (K_DIM * 16);

    const int srow = tid >> 3;
    const int sc2  = tid & 7;
    const int r16  = lane & 15;
    const int kq   = lane >> 4;
    const int kk   = tid >> 1;
    const int half = tid & 1;

    f32x4 acc[2];
    acc[0] = (f32x4){0.f, 0.f, 0.f, 0.f};
    acc[1] = (f32x4){0.f, 0.f, 0.f, 0.f};

    const float* xrow = X + (size_t)(bm0 + srow) * K_DIM + sc2 * 16;

    for (int k0 = 0; k0 < K_DIM; k0 += 128) {
        f32x4 v0 = *(const f32x4*)(xrow + k0);
        f32x4 v1 = *(const f32x4*)(xrow + k0 + 4);
        f32x4 v2 = *(const f32x4*)(xrow + k0 + 8);
        f32x4 v3 = *(const f32x4*)(xrow + k0 + 12);
        bf16x8 c0 = {(bf16_t)v0[0], (bf16_t)v0[1], (bf16_t)v0[2], (bf16_t)v0[3],
                     (bf16_t)v1[0], (bf16_t)v1[1], (bf16_t)v1[2], (bf16_t)v1[3]};
        bf16x8 c1 = {(bf16_t)v2[0], (bf16_t)v2[1], (bf16_t)v2[2], (bf16_t)v2[3],
                     (bf16_t)v3[0], (bf16_t)v3[1], (bf16_t)v3[2], (bf16_t)v3[3]};
        const int k8a = sc2 * 2, k8b = sc2 * 2 + 1;
        *(bf16x8*)(Xt + (srow * 16 + (k8a ^ (srow & 15))) * 8) = c0;
        *(bf16x8*)(Xt + (srow * 16 + (k8b ^ (srow & 15))) * 8) = c1;

        {
            const float* ap = A + (size_t)(k0 + kk) * 16 + half * 8;
            f32x4 a0 = *(const f32x4*)ap;
            f32x4 a1 = *(const f32x4*)(ap + 4);
#pragma unroll
            for (int rr = 0; rr < 4; ++rr) {
                At[(half * 8 + rr) * 136 + kk]     = (bf16_t)a0[rr];
                At[(half * 8 + 4 + rr) * 136 + kk] = (bf16_t)a1[rr];
            }
        }
        __syncthreads();

#pragma unroll
        for (int i = 0; i < 2; ++i) {
            const int row_l = i * 16 + r16;
            const int c = wave * 4 + kq;
            bf16x8 af  = *(const bf16x8*)(Xt + (row_l * 16 + (c ^ (row_l & 15))) * 8);
            bf16x8 bfr = *(const bf16x8*)(At + r16 * 136 + wave * 32 + kq * 8);
            acc[i] = __builtin_amdgcn_mfma_f32_16x16x32_bf16(af, bfr, acc[i], 0, 0, 0);
        }
        __syncthreads();
    }

#pragma unroll
    for (int i = 0; i < 2; ++i)
#pragma unroll
        for (int e = 0; e < 4; ++e)
            hred[wave * 512 + i * 256 + (kq * 4 + e) * 16 + r16] = acc[i][e];
    __syncthreads();
#pragma unroll
    for (int q = 0; q < 2; ++q) {
        const int entry = tid * 2 + q;
        const int row_l = entry >> 4, col = entry & 15;
        const int i = row_l >> 4, rr = row_l & 15;
        const int off = i * 256 + rr * 16 + col;
        float s = hred[off] + hred[512 + off] + hred[1024 + off] + hred[1536 + off];
        h_ws[(size_t)(bm0 + row_l) * 16 + col] = s * SCALE_F;
    }
}

__global__ __launch_bounds__(256) void gemm_lora_f32s(
    const float* __restrict__ Xf, const float* __restrict__ Wf,
    const float* __restrict__ bias, const float* __restrict__ lora_Bs,
    const int* __restrict__ mapping, const float* __restrict__ h_ws,
    float* __restrict__ out)
{
    __shared__ float Asf[128 * 32];
    __shared__ float Bsf[128 * 32];

    const int tid  = threadIdx.x;
    const int wave = tid >> 6;
    const int lane = tid & 63;
    const int bid  = blockIdx.x;
    const int n_t  = (bid & 7) + ((bid >> 9) << 3);
    const int m_t  = (bid >> 3) & 63;
    const int bm0 = m_t * 128;
    const int bn0 = n_t * 128;
    const int wm0 = (wave >> 1) * 64;
    const int wn0 = (wave & 1) * 64;
    const int r16 = lane & 15;
    const int kq  = lane >> 4;

    f32x4 acc[4][4];
#pragma unroll
    for (int i = 0; i < 4; ++i)
#pragma unroll
        for (int j = 0; j < 4; ++j) acc[i][j] = (f32x4){0.f, 0.f, 0.f, 0.f};

    for (int k0 = 0; k0 < K_DIM; k0 += 32) {
#pragma unroll
        for (int p = 0; p < 4; ++p) {
            const int idx0 = (p * 4 + wave) * 64;
            const int idx  = idx0 + lane;
            const int k4   = idx >> 7;
            const int row  = idx & 127;
            gload_lds16(Xf + (size_t)(bm0 + row) * K_DIM + (k0 + k4 * 4),
                        Asf + (size_t)idx0 * 4);
            gload_lds16(Wf + (size_t)(bn0 + row) * K_DIM + (k0 + k4 * 4),
                        Bsf + (size_t)idx0 * 4);
        }
        __syncthreads();

        bf16x8 af[4], bfr[4];
#pragma unroll
        for (int i = 0; i < 4; ++i) {
            const int ra = wm0 + i * 16 + r16;
            const int rb = wn0 + i * 16 + r16;
            f32x4 a0 = *(const f32x4*)(Asf + ((size_t)(kq * 2) * 128 + ra) * 4);
            f32x4 a1 = *(const f32x4*)(Asf + ((size_t)(kq * 2 + 1) * 128 + ra) * 4);
            f32x4 b0 = *(const f32x4*)(Bsf + ((size_t)(kq * 2) * 128 + rb) * 4);
            f32x4 b1 = *(const f32x4*)(Bsf + ((size_t)(kq * 2 + 1) * 128 + rb) * 4);
            af[i]  = (bf16x8){(bf16_t)a0[0], (bf16_t)a0[1], (bf16_t)a0[2], (bf16_t)a0[3],
                              (bf16_t)a1[0], (bf16_t)a1[1], (bf16_t)a1[2], (bf16_t)a1[3]};
            bfr[i] = (bf16x8){(bf16_t)b0[0], (bf16_t)b0[1], (bf16_t)b0[2], (bf16_t)b0[3],
                              (bf16_t)b1[0], (bf16_t)b1[1], (bf16_t)b1[2], (bf16_t)b1[3]};
        }
#pragma unroll
        for (int i = 0; i < 4; ++i)
#pragma unroll
            for (int j = 0; j < 4; ++j)
                acc[i][j] = __builtin_amdgcn_mfma_f32_16x16x32_bf16(af[i], bfr[j], acc[i][j], 0, 0, 0);
        __syncthreads();
    }

    const int slot = mapping[bm0 >> 10];
    const bool hasK = (kq < 2);
    const int kq2 = hasK ? kq : 0;

    bf16x8 hfrag[4], bmf[4];
#pragma unroll
    for (int i = 0; i < 4; ++i) {
        const float* hp = h_ws + (size_t)(bm0 + wm0 + i * 16 + r16) * 16 + kq2 * 8;
        f32x4 h0 = *(const f32x4*)hp;
        f32x4 h1 = *(const f32x4*)(hp + 4);
#pragma unroll
        for (int jj = 0; jj < 4; ++jj) {
            hfrag[i][jj]     = hasK ? (bf16_t)h0[jj] : (bf16_t)0.f;
            hfrag[i][jj + 4] = hasK ? (bf16_t)h1[jj] : (bf16_t)0.f;
        }
    }
#pragma unroll
    for (int j = 0; j < 4; ++j) {
        const int o = bn0 + wn0 + j * 16 + r16;
#pragma unroll
        for (int jj = 0; jj < 8; ++jj) {
            const int r = kq2 * 8 + jj;
            const float v = lora_Bs[((size_t)slot * 16 + r) * N_DIM + o];
            bmf[j][jj] = hasK ? (bf16_t)v : (bf16_t)0.f;
        }
    }
#pragma unroll
    for (int i = 0; i < 4; ++i)
#pragma unroll
        for (int j = 0; j < 4; ++j)
            acc[i][j] = __builtin_amdgcn_mfma_f32_16x16x32_bf16(hfrag[i], bmf[j], acc[i][j], 0, 0, 0);

#pragma unroll
    for (int j = 0; j < 4; ++j) {
        const int o = bn0 + wn0 + j * 16 + r16;
        const float bv = bias[o];
#pragma unroll
        for (int i = 0; i < 4; ++i) {
#pragma unroll
            for (int e = 0; e < 4; ++e) {
                const int m = bm0 + wm0 + i * 16 + kq * 4 + e;
                out[(size_t)m * N_DIM + o] = acc[i][j][e] + bv;
            }
        }
    }
}

extern "C" void kernel_launch(void* const* d_in, const int* in_sizes, int n_in,
                              void* d_out, int out_size, void* d_ws, size_t ws_size,
                              hipStream_t stream) {
    const float* x        = (const float*)d_in[0];
    const int*   mapping  = (const int*)d_in[1];
    const float* W        = (const float*)d_in[2];
    const float* b        = (const float*)d_in[3];
    const float* lora_As  = (const float*)d_in[4];
    const float* lora_Bs  = (const float*)d_in[5];
    float* out = (float*)d_out;

    const size_t xb_bytes = (size_t)M_DIM * K_DIM * 2;   // 64 MB
    const size_t wb_bytes = (size_t)N_DIM * K_DIM * 2;   // 32 MB
    const bool direct = ws_size >= xb_bytes + wb_bytes;

    if (direct) {
        bf16_t* Xb = (bf16_t*)d_ws;
        bf16_t* Wb = (bf16_t*)((char*)d_ws + xb_bytes);
        cvt_all<<<dim3(CVT_BLOCKS), 256, 0, stream>>>(x, Xb, W, Wb);
        gemm_lora_direct<<<dim3(1024), 256, 0, stream>>>(
            Xb, Wb, b, lora_As, lora_Bs, mapping, out, 0);
        gemm_lora_direct<<<dim3(1024), 256, 0, stream>>>(
            Xb, Wb, b, lora_As, lora_Bs, mapping, out, 32);
    } else {
        float* h_ws = (float*)d_ws;   // 512 KB
        prep_fallback<<<dim3(M_DIM / 32), 256, 0, stream>>>(
            x, lora_As, mapping, h_ws);
        gemm_lora_f32s<<<dim3(2048), 256, 0, stream>>>(
            x, W, b, lora_Bs, mapping, h_ws, out);
    }
}